// Round 1
// baseline (117.833 us; speedup 1.0000x reference)
//
#include <hip/hip_runtime.h>

// Problem dims (from reference setup_inputs)
#define BB 4
#define CC 64
#define HH 256
#define WW 256
#define NPIX (HH*WW)          // 65536
#define NCLS 4
#define NPAIR 12              // B*(NCLS-1)
#define HALF 512
#define MAXS 1024
#define CHUNK 4096
#define NCHUNK (NPIX/CHUNK)   // 16
#define TPB 256
#define PXT (CHUNK/TPB)       // 16 pixels per thread (contiguous, raster order)

// K1: per-pixel argmax over the 4 class logits (first-max wins, like jnp.argmax)
__global__ void k_argmax(const float* __restrict__ preds, unsigned char* __restrict__ amax) {
    int i = blockIdx.x * blockDim.x + threadIdx.x;
    if (i >= BB * NPIX) return;
    int b = i >> 16;
    int pix = i & (NPIX - 1);
    const float* p = preds + (size_t)b * NCLS * NPIX + pix;
    float best = p[0];
    int arg = 0;
#pragma unroll
    for (int c = 1; c < NCLS; ++c) {
        float v = p[(size_t)c * NPIX];
        if (v > best) { best = v; arg = c; }
    }
    amax[i] = (unsigned char)arg;
}

// K2: 3x3 max "dilation", SAME padding (clipped window)
__global__ void k_dilate(const unsigned char* __restrict__ amax, unsigned char* __restrict__ pd) {
    int i = blockIdx.x * blockDim.x + threadIdx.x;
    if (i >= BB * NPIX) return;
    int b = i >> 16;
    int pix = i & (NPIX - 1);
    int y = pix >> 8;
    int x = pix & (WW - 1);
    const unsigned char* base = amax + b * NPIX;
    int mv = 0;
    for (int dy = -1; dy <= 1; ++dy) {
        int yy = y + dy;
        if (yy < 0 || yy >= HH) continue;
        for (int dx = -1; dx <= 1; ++dx) {
            int xx = x + dx;
            if (xx < 0 || xx >= WW) continue;
            int v = base[yy * WW + xx];
            if (v > mv) mv = v;
        }
    }
    pd[i] = (unsigned char)mv;
}

// K3: per-(pair, chunk) hard/easy counts, packed hard | easy<<16
__global__ void k_count(const int* __restrict__ labels, const unsigned char* __restrict__ pd,
                        unsigned* __restrict__ chunkCounts) {
    int pair = blockIdx.x, chunk = blockIdx.y, t = threadIdx.x;
    int b = pair / 3, cls = pair % 3 + 1;
    const int* lab = labels + b * NPIX;
    const unsigned char* p = pd + b * NPIX;
    int start = chunk * CHUNK + t * PXT;
    int hc = 0, ec = 0;
#pragma unroll
    for (int j = 0; j < PXT; ++j) {
        int pix = start + j;
        int l = lab[pix];
        int d = p[pix];
        if (l == cls) { if (d == cls) ec++; else hc++; }
    }
    __shared__ unsigned s[TPB];
    s[t] = (unsigned)hc | ((unsigned)ec << 16);
    __syncthreads();
    for (int off = TPB / 2; off > 0; off >>= 1) {
        if (t < off) s[t] += s[t + off];
        __syncthreads();
    }
    if (t == 0) chunkCounts[pair * NCHUNK + chunk] = s[0];
}

// K4: tiny scan of chunk counts per pair -> chunk base ranks + hard totals; init slots to -1
__global__ void k_scan(const unsigned* __restrict__ chunkCounts, int2* __restrict__ chunkBases,
                       int* __restrict__ hardTotals, int* __restrict__ slots) {
    int t = threadIdx.x;
    if (t < NPAIR) {
        int hb = 0, eb = 0;
        for (int ch = 0; ch < NCHUNK; ++ch) {
            unsigned v = chunkCounts[t * NCHUNK + ch];
            chunkBases[t * NCHUNK + ch] = make_int2(hb, eb);
            hb += (int)(v & 0xffffu);
            eb += (int)(v >> 16);
        }
        hardTotals[t] = hb;
    }
    for (int i = t; i < NPAIR * MAXS; i += blockDim.x) slots[i] = -1;
}

// K5: assign pixel indices to output slots via global raster ranks
//  hard rank r  -> slot r            (if r < 1024)
//  easy rank e  -> slot 512+excess+e (if < 1024), excess = max(num_hard-512, 0)
__global__ void k_assign(const int* __restrict__ labels, const unsigned char* __restrict__ pd,
                         const int2* __restrict__ chunkBases, const int* __restrict__ hardTotals,
                         int* __restrict__ slots) {
    int pair = blockIdx.x, chunk = blockIdx.y, t = threadIdx.x;
    int b = pair / 3, cls = pair % 3 + 1;
    const int* lab = labels + b * NPIX;
    const unsigned char* p = pd + b * NPIX;
    int start = chunk * CHUNK + t * PXT;
    int hc = 0, ec = 0;
#pragma unroll
    for (int j = 0; j < PXT; ++j) {
        int pix = start + j;
        int l = lab[pix];
        int d = p[pix];
        if (l == cls) { if (d == cls) ec++; else hc++; }
    }
    __shared__ unsigned s[TPB];
    unsigned mine = (unsigned)hc | ((unsigned)ec << 16);
    s[t] = mine;
    __syncthreads();
    // Hillis-Steele inclusive scan (packed)
    for (int off = 1; off < TPB; off <<= 1) {
        unsigned v = (t >= off) ? s[t - off] : 0u;
        __syncthreads();
        s[t] += v;
        __syncthreads();
    }
    unsigned excl = s[t] - mine;
    int2 base = chunkBases[pair * NCHUNK + chunk];
    int hr = base.x + (int)(excl & 0xffffu);
    int er = base.y + (int)(excl >> 16);
    int excess = hardTotals[pair] - HALF;
    if (excess < 0) excess = 0;
    int* sl = slots + pair * MAXS;
#pragma unroll
    for (int j = 0; j < PXT; ++j) {
        int pix = start + j;
        int l = lab[pix];
        int d = p[pix];
        if (l == cls) {
            if (d != cls) {
                if (hr < MAXS) sl[hr] = pix;
                hr++;
            } else {
                int pos = HALF + excess + er;
                if (pos < MAXS) sl[pos] = pix;
                er++;
            }
        }
    }
}

// K6: gather features (zero for invalid slots) + write class labels
__global__ void k_gather(const float* __restrict__ feat, const int* __restrict__ slots,
                         float* __restrict__ out) {
    int i = blockIdx.x * blockDim.x + threadIdx.x;
    const int NOUT = NPAIR * CC * MAXS;
    if (i < NOUT) {
        int pair = i / (CC * MAXS);
        int c = (i >> 10) & (CC - 1);
        int slot = i & (MAXS - 1);
        int pix = slots[pair * MAXS + slot];
        int b = pair / 3;
        out[i] = (pix >= 0) ? feat[((size_t)(b * CC + c)) * NPIX + pix] : 0.0f;
    } else if (i < NOUT + NPAIR) {
        int pair = i - NOUT;
        out[i] = (float)(pair % 3 + 1);
    }
}

extern "C" void kernel_launch(void* const* d_in, const int* in_sizes, int n_in,
                              void* d_out, int out_size, void* d_ws, size_t ws_size,
                              hipStream_t stream) {
    const float* feat   = (const float*)d_in[0];  // [B,C,H,W] fp32
    const int*   labels = (const int*)d_in[1];    // [B,H,W] int32
    const float* preds  = (const float*)d_in[2];  // [B,NCLS,H,W] fp32
    float* out = (float*)d_out;

    // workspace layout (byte buffers first, then ints; all comfortably < 1 MB)
    unsigned char* amax = (unsigned char*)d_ws;              // B*NPIX bytes
    unsigned char* pd   = amax + BB * NPIX;                  // B*NPIX bytes
    unsigned* chunkCounts = (unsigned*)(pd + BB * NPIX);     // NPAIR*NCHUNK
    int2* chunkBases = (int2*)(chunkCounts + NPAIR * NCHUNK); // NPAIR*NCHUNK (8B aligned: offset 524288+768)
    int* hardTotals = (int*)(chunkBases + NPAIR * NCHUNK);   // NPAIR
    int* slots = hardTotals + NPAIR;                         // NPAIR*MAXS

    int npx = BB * NPIX;
    k_argmax<<<npx / 256, 256, 0, stream>>>(preds, amax);
    k_dilate<<<npx / 256, 256, 0, stream>>>(amax, pd);
    dim3 g(NPAIR, NCHUNK);
    k_count<<<g, TPB, 0, stream>>>(labels, pd, chunkCounts);
    k_scan<<<1, 256, 0, stream>>>(chunkCounts, chunkBases, hardTotals, slots);
    k_assign<<<g, TPB, 0, stream>>>(labels, pd, chunkBases, hardTotals, slots);
    int nout = NPAIR * CC * MAXS + NPAIR;
    k_gather<<<(nout + 255) / 256, 256, 0, stream>>>(feat, slots, out);
}